// Round 12
// baseline (234.990 us; speedup 1.0000x reference)
//
#include <hip/hip_runtime.h>
#include <hip/hip_bf16.h>

typedef __attribute__((ext_vector_type(8))) unsigned short us8;
typedef __attribute__((ext_vector_type(8))) __bf16 bf16x8;
typedef __attribute__((ext_vector_type(4))) float f32x4;

__device__ __forceinline__ unsigned short f2bf(float f) {
  unsigned int u = __float_as_uint(f);
  u += 0x7FFFu + ((u >> 16) & 1u);   // round-to-nearest-even
  return (unsigned short)(u >> 16);
}
__device__ __forceinline__ float bf2f(unsigned short u) {
  return __uint_as_float(((unsigned int)u) << 16);
}

// direct global->LDS DMA, 16B per lane (dest = wave-uniform base + lane*16)
__device__ __forceinline__ void gld16(const unsigned short* g, unsigned short* l) {
  __builtin_amdgcn_global_load_lds(reinterpret_cast<const unsigned int*>(g),
                                   reinterpret_cast<unsigned int*>(l), 16, 0, 0);
}

// ---------------------------------------------------------------------------
// ws layout (bytes)
//   Apad : [2][132][132][256] bf16 = 17,842,176
//   BT   : [256][6400] bf16 (k=(dh*5+dw)*256+c)
//   Pp   : 2 x [32768][256] bf16 partials = 33,554,432
// total = 54,673,408
// ---------------------------------------------------------------------------
#define BT_OFF     17842176
#define PP_OFF     21118976

// --- K1: fused conv1 (blocks 0..4095) + weight prep (4096..4351) +
//         halo zero (4352..4611) --------------------------------------------
__global__ __launch_bounds__(256) void pre_k(const float* __restrict__ x,
                                             const float* __restrict__ W1,
                                             const float* __restrict__ b1,
                                             const float* __restrict__ Wp,
                                             unsigned short* __restrict__ BT,
                                             unsigned short* __restrict__ Apad) {
  __shared__ float w[6400];
  const int bid = blockIdx.x, t = threadIdx.x;
  if (bid < 4096) {
    int pxt = bid >> 3;
    int cq  = bid & 7;
    int px  = (pxt << 6) + (t & 63);
    int cg  = __builtin_amdgcn_readfirstlane(t >> 6);
    int co0 = (cq << 5) + (cg << 3);
    int b = px >> 14, hw = px & 16383;
    int h = hw >> 7, wcol = hw & 127;

    float patch[25];
#pragma unroll
    for (int dh = 0; dh < 5; ++dh)
#pragma unroll
      for (int dw = 0; dw < 5; ++dw) {
        int hh = h + dh - 2, ww = wcol + dw - 2;
        bool ok = (hh >= 0) & (hh < 128) & (ww >= 0) & (ww < 128);
        patch[dh * 5 + dw] = ok ? x[(b << 14) + hh * 128 + ww] : 0.f;
      }
    us8 o;
#pragma unroll
    for (int c = 0; c < 8; ++c) {
      float acc = b1[co0 + c];
#pragma unroll
      for (int i = 0; i < 25; ++i) acc += patch[i] * W1[(co0 + c) * 25 + i];
      o[c] = f2bf(fmaxf(acc, 0.f));
    }
    *(us8*)(Apad + (size_t)((b * 132 + h + 2) * 132 + (wcol + 2)) * 256 + co0) = o;
  } else if (bid < 4352) {
    const int n = bid - 4096;
    const float* src = Wp + n * 6400;
    for (int i = t; i < 6400; i += 256) w[i] = src[i];
    __syncthreads();
    for (int k = t; k < 6400; k += 256) {
      int dhw = k >> 8, c = k & 255;
      BT[n * 6400 + k] = f2bf(w[c * 25 + dhw]);
    }
  } else {
    int idx = (bid - 4352) * 256 + t;
    int chunk = idx & 31;
    int pix = idx >> 5;
    int img = pix >= 1040;
    int p = pix - img * 1040;
    int h, w2;
    if (p < 528) {
      int rs = p / 132;
      h = (rs < 2) ? rs : rs + 128;
      w2 = p - rs * 132;
    } else {
      int q = p - 528;
      h = 2 + (q >> 2);
      int cs = q & 3;
      w2 = (cs < 2) ? cs : cs + 128;
    }
    us8 z = {0, 0, 0, 0, 0, 0, 0, 0};
    *(us8*)(Apad + (size_t)(img * 17424 + h * 132 + w2) * 256 + chunk * 8) = z;
  }
}

// --- K2: implicit-GEMM conv, 256x256 tile, 8 waves, BK=64 units ------------
// 2-slot ring (A[256][64]+B[256][64] bf16 per slot = 64 KB, 128 KB total).
// ONE barrier + ONE counted VMC(8) per 64-K unit (half the r8 body count).
//   body b: STAGE(slot b&1, unit b+2) ; VMC(8) [drains unit b+1's stage,
//           issued a full body ago] ; MFMA(unit b, regs read last body) ;
//           READ(unit b+1, slot (b+1)&1) ; sched_barrier ; s_barrier
// Slot WAR: stage(slot b&1) vs reads of that slot at body b-1 = 1-barrier
// separation (m201-proven idiom). Single-buffered frags: MFMA precedes the
// READ that overwrites them (in-order issue honors the WAR).
// Swizzle (128B rows, 8x16B parts): stage source part (l&7)^(l>>3); read
// part (h*4+q)^(rl&7) -> 2 lanes/bank (free, m136).
#define STAGE64(slot, g) do {                                                  \
    int tap_ = (g) >> 2, dh_ = tap_ / 5, dw_ = tap_ - dh_ * 5;                 \
    int ao_ = ((dh_ * 132 + dw_) << 8) + (((g) & 3) << 6);                     \
    int kp_ = (g) << 6;                                                        \
    _Pragma("unroll") for (int j_ = 0; j_ < 4; ++j_) {                         \
      gld16(Aap + abaseA[j_] + ao_, &As[slot][(wid * 32 + j_ * 8) * 64]);      \
      gld16(BT + bbaseB[j_] + kp_, &Bs[slot][(wid * 32 + j_ * 8) * 64]);       \
    } } while(0)
#define READ64(slot) do {                                                      \
  _Pragma("unroll") for (int h_ = 0; h_ < 2; ++h_) {                           \
    _Pragma("unroll") for (int s_ = 0; s_ < 8; ++s_)                           \
      aF[h_][s_] = *(const bf16x8*)(&As[slot][areadbase + s_ * 1024 + kpart[h_]]); \
    _Pragma("unroll") for (int j_ = 0; j_ < 4; ++j_)                           \
      bF[h_][j_] = *(const bf16x8*)(&Bs[slot][breadbase + j_ * 1024 + kpart[h_]]); \
  } } while(0)
#define MFMA64() do {                                                          \
  _Pragma("unroll") for (int h_ = 0; h_ < 2; ++h_)                             \
  _Pragma("unroll") for (int s_ = 0; s_ < 8; ++s_)                             \
  _Pragma("unroll") for (int j_ = 0; j_ < 4; ++j_)                             \
    acc[s_][j_] = __builtin_amdgcn_mfma_f32_16x16x32_bf16(                     \
        aF[h_][s_], bF[h_][j_], acc[s_][j_], 0, 0, 0); } while(0)
#define BAR() __builtin_amdgcn_s_barrier()
#define VMC(n) asm volatile("s_waitcnt vmcnt(" #n ")" ::: "memory")
#define SB0() __builtin_amdgcn_sched_barrier(0)
#define SP(n) __builtin_amdgcn_s_setprio(n)

__global__ __launch_bounds__(512, 1) void caps_conv2(
    const unsigned short* __restrict__ Aap,  // Apad NHWC bf16
    const unsigned short* __restrict__ BT,   // [256][6400] bf16
    unsigned short* __restrict__ Pp)         // 2 x [32768][256] bf16 partials
{
  __shared__ __attribute__((aligned(16))) unsigned short As[2][16384];
  __shared__ __attribute__((aligned(16))) unsigned short Bs[2][16384];

  const int tid = threadIdx.x;
  const int bid = blockIdx.x;          // 256 blocks
  const int lid = (bid & 7) * 32 + (bid >> 3);   // bijective XCD-chunked swizzle
  const int kid = lid & 1;
  const int m0 = (lid >> 1) << 8;
  const int t0 = kid * 50;             // 50 k-units of 64 per split-K half
  const int wid = tid >> 6;
  const int l = tid & 63;

  // --- staging bases: instr j covers rows wid*32 + j*8 + (l>>3) ---
  const int ps = ((l & 7) ^ (l >> 3)) * 8;      // pre-swizzled 16B part
  int abaseA[4], bbaseB[4];
#pragma unroll
  for (int j = 0; j < 4; ++j) {
    int ra = wid * 32 + j * 8 + (l >> 3);       // 0..255
    int m = m0 + ra;
    int b = m >> 14, hw = m & 16383, h = hw >> 7, w = hw & 127;
    abaseA[j] = ((b * 132 + h) * 132 + w) * 256 + ps;
    bbaseB[j] = ra * 6400 + ps;
  }

  // --- fragment-read addresses ---
  const int rl = l & 15, q = l >> 4;
  const int wm = wid >> 2, wn = wid & 3;        // 2x4 wave grid, tile 128x64
  const int areadbase = (wm * 128 + rl) * 64;
  const int breadbase = (wn * 64 + rl) * 64;
  int kpart[2];
  kpart[0] = ((q) ^ (rl & 7)) * 8;
  kpart[1] = ((4 + q) ^ (rl & 7)) * 8;

  f32x4 acc[8][4] = {};
  bf16x8 aF[2][8], bF[2][4];

  // --- prologue: stage units 0,1; wait unit 0; read its frags ---
  STAGE64(0, t0 + 0);
  STAGE64(1, t0 + 1);
  VMC(8); BAR();                       // unit 0 landed (unit 1's 8 in flight)
  READ64(0);
  SB0(); BAR();                        // protect slot 0 from body-0 stage

  // --- main loop: bodies 0..47 (24 iters x 2) ---
  for (int it = 0; it < 24; ++it) {
    const int b = it * 2;
    // body b (even): slot parity 0
    STAGE64(0, t0 + b + 2);
    VMC(8);                            // drain unit b+1 (staged last body)
    SP(1); MFMA64(); SP(0);            // unit b (regs)
    READ64(1);                         // unit b+1 frags
    SB0(); BAR();
    // body b+1 (odd): slot parity 1
    STAGE64(1, t0 + b + 3);
    VMC(8);
    SP(1); MFMA64(); SP(0);            // unit b+1
    READ64(0);                         // unit b+2 frags
    SB0(); BAR();
  }
  // body 48: no stage; drain unit 49 (staged at body 47)
  VMC(0);
  SP(1); MFMA64(); SP(0);              // unit 48
  READ64(1);                           // unit 49 (slot 1)
  // body 49 (compiler inserts lgkm waits)
  MFMA64();

  // --- epilogue: raw bf16 partial store (squash + bias in tail kernel) ---
  unsigned short* P = Pp + kid * 8388608;
#pragma unroll
  for (int s = 0; s < 8; ++s) {
#pragma unroll
    for (int j = 0; j < 4; ++j) {
      int col = wn * 64 + j * 16 + rl;
      int mrow = m0 + wm * 128 + s * 16 + (q << 2);
#pragma unroll
      for (int e = 0; e < 4; ++e)
        P[(size_t)(mrow + e) * 256 + col] = f2bf(acc[s][j][e]);
    }
  }
}

// --- K3: tail, scalarized weights (r11 config) ------------------------------
__global__ __launch_bounds__(128) void tail_k4(
    const unsigned short* __restrict__ Pp, const float* __restrict__ y,
    const float* __restrict__ bp, const float* __restrict__ cbp,
    const float* __restrict__ Ws, const float* __restrict__ bs,
    const float* __restrict__ cbs,
    const float* __restrict__ Wr1, const float* __restrict__ br1,
    const float* __restrict__ Wr2, const float* __restrict__ br2,
    const float* __restrict__ Wr3, const float* __restrict__ br3,
    float* __restrict__ out) {
  __shared__ float pp[2][64][8];
  __shared__ float r1l[64][65];
  __shared__ float snk[2][64];

  const int tid = threadIdx.x;
  const int w = __builtin_amdgcn_readfirstlane(tid >> 6);
  const int l = tid & 63;
  const int m = blockIdx.x * 64 + l;

  const us8* pr0 = (const us8*)(Pp + (size_t)m * 256) + w * 16;
  const us8* pr1 = (const us8*)(Pp + 8388608 + (size_t)m * 256) + w * 16;
  float P8[8] = {0.f, 0.f, 0.f, 0.f, 0.f, 0.f, 0.f, 0.f};
#pragma unroll 4
  for (int i = 0; i < 16; ++i) {
    const int ci = (w * 16 + i) * 8;
    us8 a = pr0[i], b = pr1[i];
    float v[8];
#pragma unroll
    for (int c = 0; c < 8; ++c)
      v[c] = (bf2f(a[c]) + bf2f(b[c])) * (1.f / 32.f)
           + (bp[ci + c] * (1.f / 32.f) + cbp[ci + c]);
    float sqa = v[0]*v[0] + v[1]*v[1] + v[2]*v[2] + v[3]*v[3];
    float sqb = v[4]*v[4] + v[5]*v[5] + v[6]*v[6] + v[7]*v[7];
    float sq = sqa + sqb;
    float scale = sq / ((1.f + sq) * sqrtf(sq + 1e-9f));
#pragma unroll
    for (int c = 0; c < 8; ++c) P8[c] += v[c] * scale;
  }
#pragma unroll
  for (int c = 0; c < 8; ++c) pp[w][l][c] = P8[c];
  __syncthreads();
#pragma unroll
  for (int c = 0; c < 8; ++c) P8[c] = pp[0][l][c] + pp[1][l][c];

  float pre[16];
  float sqx = 0.f, sqy = 0.f;
#pragma unroll
  for (int a = 0; a < 16; ++a) {
    float s0 = P8[0]*Ws[a*8+0] + P8[1]*Ws[a*8+1] + P8[2]*Ws[a*8+2] + P8[3]*Ws[a*8+3];
    float s1 = P8[4]*Ws[a*8+4] + P8[5]*Ws[a*8+5] + P8[6]*Ws[a*8+6] + P8[7]*Ws[a*8+7];
    float s = (32.f * bs[a] + cbs[a]) + s0 + s1;
    pre[a] = s;
    if (a & 1) sqy += s * s; else sqx += s * s;
  }
  float sq2 = sqx + sqy;
  float sc2 = sq2 / ((1.f + sq2) * sqrtf(sq2 + 1e-9f));
  if (w == 0) out[m] = sqrtf(sq2 * sc2 * sc2 + 1e-9f);

  const float f = sc2 * y[m];
  float pf[16];
#pragma unroll
  for (int a = 0; a < 16; ++a) pf[a] = pre[a] * f;

#pragma unroll
  for (int jj = 0; jj < 32; ++jj) {
    const int j = w * 32 + jj;
    float s0 = 0.f, s1 = 0.f;
#pragma unroll
    for (int a = 0; a < 8; ++a) {
      s0 += pf[a] * Wr1[j * 16 + a];
      s1 += pf[a + 8] * Wr1[j * 16 + a + 8];
    }
    r1l[l][j] = fmaxf(br1[j] + s0 + s1, 0.f);
  }
  __syncthreads();
  float r1f[64];
#pragma unroll
  for (int j = 0; j < 64; ++j) r1f[j] = r1l[l][j];

  float a0 = 0.f, a1 = 0.f, a2 = 0.f, a3 = 0.f;
#pragma unroll 4
  for (int kk = 0; kk < 64; ++kk) {
    const int k = w * 64 + kk;
    const float* wr = Wr2 + k * 64;
    float s0 = 0.f, s1 = 0.f, s2 = 0.f, s3 = 0.f;
#pragma unroll
    for (int j = 0; j < 16; ++j) {
      s0 += r1f[j] * wr[j];           s1 += r1f[j + 16] * wr[j + 16];
      s2 += r1f[j + 32] * wr[j + 32]; s3 += r1f[j + 48] * wr[j + 48];
    }
    float s = br2[k] + (s0 + s1) + (s2 + s3);
    float t = fmaxf(s, 0.f) * Wr3[k];
    switch (kk & 3) { case 0: a0 += t; break; case 1: a1 += t; break;
                      case 2: a2 += t; break; default: a3 += t; }
  }
  float own = (a0 + a1) + (a2 + a3);
  snk[w][l] = own;
  __syncthreads();
  if (w == 0) {
    float acc2 = br3[0] + own + snk[1][l];
    out[32768 + m] = 1.f / (1.f + expf(-acc2));
  }
}

// ---------------------------------------------------------------------------
extern "C" void kernel_launch(void* const* d_in, const int* in_sizes, int n_in,
                              void* d_out, int out_size, void* d_ws, size_t ws_size,
                              hipStream_t stream) {
  const float* x   = (const float*)d_in[0];
  const float* y   = (const float*)d_in[1];
  const float* W1  = (const float*)d_in[2];
  const float* b1  = (const float*)d_in[3];
  const float* Wp  = (const float*)d_in[4];
  const float* bp  = (const float*)d_in[5];
  const float* cbp = (const float*)d_in[6];
  const float* Ws  = (const float*)d_in[7];
  const float* bs  = (const float*)d_in[8];
  const float* cbs = (const float*)d_in[9];
  const float* Wr1 = (const float*)d_in[10];
  const float* br1 = (const float*)d_in[11];
  const float* Wr2 = (const float*)d_in[12];
  const float* br2 = (const float*)d_in[13];
  const float* Wr3 = (const float*)d_in[14];
  const float* br3 = (const float*)d_in[15];
  float* out = (float*)d_out;

  char* ws = (char*)d_ws;
  unsigned short* Apad = (unsigned short*)ws;
  unsigned short* BT   = (unsigned short*)(ws + BT_OFF);
  unsigned short* Pp   = (unsigned short*)(ws + PP_OFF);

  hipLaunchKernelGGL(pre_k, dim3(4612), dim3(256), 0, stream, x, W1, b1, Wp, BT, Apad);
  hipLaunchKernelGGL(caps_conv2, dim3(256), dim3(512), 0, stream, Apad, BT, Pp);
  hipLaunchKernelGGL(tail_k4, dim3(512), dim3(128), 0, stream,
                     Pp, y, bp, cbp, Ws, bs, cbs, Wr1, br1, Wr2, br2, Wr3, br3, out);
}

// Round 13
// 157.595 us; speedup vs baseline: 1.4911x; 1.4911x over previous
//
#include <hip/hip_runtime.h>
#include <hip/hip_bf16.h>

typedef __attribute__((ext_vector_type(8))) unsigned short us8;
typedef __attribute__((ext_vector_type(8))) __bf16 bf16x8;
typedef __attribute__((ext_vector_type(16))) float f32x16;

__device__ __forceinline__ unsigned short f2bf(float f) {
  unsigned int u = __float_as_uint(f);
  u += 0x7FFFu + ((u >> 16) & 1u);   // round-to-nearest-even
  return (unsigned short)(u >> 16);
}
__device__ __forceinline__ float bf2f(unsigned short u) {
  return __uint_as_float(((unsigned int)u) << 16);
}

// direct global->LDS DMA, 16B per lane (dest = wave-uniform base + lane*16)
__device__ __forceinline__ void gld16(const unsigned short* g, unsigned short* l) {
  __builtin_amdgcn_global_load_lds(reinterpret_cast<const unsigned int*>(g),
                                   reinterpret_cast<unsigned int*>(l), 16, 0, 0);
}

// ---------------------------------------------------------------------------
// ws layout (bytes)
//   Apad : [2][132][132][256] bf16 = 17,842,176
//   BT   : [256][6400] bf16 (k=(dh*5+dw)*256+c)
//   Pp   : 2 x [32768][256] bf16 partials = 33,554,432
// total = 54,673,408
// ---------------------------------------------------------------------------
#define BT_OFF     17842176
#define PP_OFF     21118976

// --- K1: fused conv1 (blocks 0..4095) + weight prep (4096..4351) +
//         halo zero (4352..4611) --------------------------------------------
__global__ __launch_bounds__(256) void pre_k(const float* __restrict__ x,
                                             const float* __restrict__ W1,
                                             const float* __restrict__ b1,
                                             const float* __restrict__ Wp,
                                             unsigned short* __restrict__ BT,
                                             unsigned short* __restrict__ Apad) {
  __shared__ float w[6400];
  const int bid = blockIdx.x, t = threadIdx.x;
  if (bid < 4096) {
    int pxt = bid >> 3;
    int cq  = bid & 7;
    int px  = (pxt << 6) + (t & 63);
    int cg  = __builtin_amdgcn_readfirstlane(t >> 6);
    int co0 = (cq << 5) + (cg << 3);
    int b = px >> 14, hw = px & 16383;
    int h = hw >> 7, wcol = hw & 127;

    float patch[25];
#pragma unroll
    for (int dh = 0; dh < 5; ++dh)
#pragma unroll
      for (int dw = 0; dw < 5; ++dw) {
        int hh = h + dh - 2, ww = wcol + dw - 2;
        bool ok = (hh >= 0) & (hh < 128) & (ww >= 0) & (ww < 128);
        patch[dh * 5 + dw] = ok ? x[(b << 14) + hh * 128 + ww] : 0.f;
      }
    us8 o;
#pragma unroll
    for (int c = 0; c < 8; ++c) {
      float acc = b1[co0 + c];
#pragma unroll
      for (int i = 0; i < 25; ++i) acc += patch[i] * W1[(co0 + c) * 25 + i];
      o[c] = f2bf(fmaxf(acc, 0.f));
    }
    *(us8*)(Apad + (size_t)((b * 132 + h + 2) * 132 + (wcol + 2)) * 256 + co0) = o;
  } else if (bid < 4352) {
    const int n = bid - 4096;
    const float* src = Wp + n * 6400;
    for (int i = t; i < 6400; i += 256) w[i] = src[i];
    __syncthreads();
    for (int k = t; k < 6400; k += 256) {
      int dhw = k >> 8, c = k & 255;
      BT[n * 6400 + k] = f2bf(w[c * 25 + dhw]);
    }
  } else {
    int idx = (bid - 4352) * 256 + t;
    int chunk = idx & 31;
    int pix = idx >> 5;
    int img = pix >= 1040;
    int p = pix - img * 1040;
    int h, w2;
    if (p < 528) {
      int rs = p / 132;
      h = (rs < 2) ? rs : rs + 128;
      w2 = p - rs * 132;
    } else {
      int q = p - 528;
      h = 2 + (q >> 2);
      int cs = q & 3;
      w2 = (cs < 2) ? cs : cs + 128;
    }
    us8 z = {0, 0, 0, 0, 0, 0, 0, 0};
    *(us8*)(Apad + (size_t)(img * 17424 + h * 132 + w2) * 256 + chunk * 8) = z;
  }
}

// --- K2: implicit-GEMM conv, r8 skeleton + 32x32x16 MFMA -------------------
// 256x256 tile, 8 waves, split-K=2, 4-slot BK=32 ring (A+B in LDS, 128 KB),
// reg-double-buffered frags, ONE barrier + ONE counted VMC(4) per k-unit.
// MFMA = v_mfma_f32_32x32x16_bf16 (2382 TF ubench vs 2075 for 16x16):
//   wave tile 128x64 = 4 row-tiles x 2 col-tiles of 32x32, 2 k-steps/unit
//   A frag: row=l&31, k=(l>>5)*8+[0,8)  (analog of verified 16x16 pattern)
//   C/D   : col=lane&31, row=(reg&3)+8*(reg>>2)+4*(lane>>5)  [m74/m101]
// Swizzle pair for 32-row frags (64B rows, 4x16B parts), conflict-free:
//   f(row) = ((row>>1)&3)^((row>>3)&3); stage source part = (l&3)^f(row_l)
//   with row_l = wid*16+(l>>2) -> (l>>3)&3 ^ ((l>>5)&1 | (wid&1)<<1).
#define STAGE(slot, ku) do { int dhw_=(ku)>>3, dh_=dhw_/5, dw_=dhw_-dh_*5;     \
    int ao_=((dh_*132+dw_)<<8)+(((ku)&7)<<5);                                  \
    int kp_=(ku)<<5;                                                           \
    gld16(Aap+abase0+ao_, &As[slot][sA]);                                      \
    gld16(Aap+abase1+ao_, &As[slot][sA+4096]);                                 \
    gld16(BT+bbase0+kp_, &Bs[slot][sA]);                                       \
    gld16(BT+bbase1+kp_, &Bs[slot][sA+4096]); } while(0)
#define READ_SET(AST, BST, slot) do {                                          \
  _Pragma("unroll") for (int t_ = 0; t_ < 4; ++t_)                             \
  _Pragma("unroll") for (int s_ = 0; s_ < 2; ++s_)                             \
    AST[t_][s_] = *(const bf16x8*)(&As[slot][arb[t_] + kp[s_]]);               \
  _Pragma("unroll") for (int c_ = 0; c_ < 2; ++c_)                             \
  _Pragma("unroll") for (int s_ = 0; s_ < 2; ++s_)                             \
    BST[c_][s_] = *(const bf16x8*)(&Bs[slot][brb[c_] + kp[s_]]); } while(0)
#define MFMA_SET(AST, BST) do {                                                \
  _Pragma("unroll") for (int s_ = 0; s_ < 2; ++s_)                             \
  _Pragma("unroll") for (int t_ = 0; t_ < 4; ++t_)                             \
  _Pragma("unroll") for (int c_ = 0; c_ < 2; ++c_)                             \
    acc[t_][c_] = __builtin_amdgcn_mfma_f32_32x32x16_bf16(                     \
        AST[t_][s_], BST[c_][s_], acc[t_][c_], 0, 0, 0); } while(0)
#define BAR() __builtin_amdgcn_s_barrier()
#define VMC(n) asm volatile("s_waitcnt vmcnt(" #n ")" ::: "memory")
#define SB0() __builtin_amdgcn_sched_barrier(0)
#define SP(n) __builtin_amdgcn_s_setprio(n)

__global__ __launch_bounds__(512, 1) void caps_conv2(
    const unsigned short* __restrict__ Aap,  // Apad NHWC bf16
    const unsigned short* __restrict__ BT,   // [256][6400] bf16
    unsigned short* __restrict__ Pp)         // 2 x [32768][256] bf16 partials
{
  __shared__ __attribute__((aligned(16))) unsigned short As[4][8192];
  __shared__ __attribute__((aligned(16))) unsigned short Bs[4][8192];

  const int tid = threadIdx.x;
  const int bid = blockIdx.x;          // 256 blocks
  const int lid = (bid & 7) * 32 + (bid >> 3);   // bijective XCD-chunked swizzle
  const int kid = lid & 1;
  const int m0 = (lid >> 1) << 8;
  const int t0 = kid * 100;            // 100 k-units of 32 per split-K half
  const int wid = tid >> 6;
  const int l = tid & 63;

  // staging source part: (l&3) ^ f(row_l), row_l = wid*16 + (l>>2)
  const int swz = (l & 3) ^ ((l >> 3) & 3) ^ ((l >> 5) & 1) ^ ((wid & 1) << 1);
  int abase0, abase1, bbase0, bbase1;
  {
    int ra = wid * 16 + (l >> 2);               // 0..127
    int m = m0 + ra;
    int b = m >> 14, hw = m & 16383, h = hw >> 7, w = hw & 127;
    abase0 = ((b * 132 + h) * 132 + w) * 256 + swz * 8;
    m = m0 + ra + 128;
    b = m >> 14; hw = m & 16383; h = hw >> 7; w = hw & 127;
    abase1 = ((b * 132 + h) * 132 + w) * 256 + swz * 8;
    bbase0 = ra * 6400 + swz * 8;
    bbase1 = (ra + 128) * 6400 + swz * 8;
  }
  const int sA = wid * 512;            // LDS stage base (ushorts)

  // --- fragment-read addresses (32-row tiles) ---
  const int rr = l & 31;               // row within 32-row tile
  const int q5 = l >> 5;               // k-half selector
  const int wm = wid >> 2, wn = wid & 3;        // 2x4 wave grid, tile 128x64
  const int fx = ((rr >> 1) & 3) ^ ((rr >> 3) & 3);
  int kp[2];
  kp[0] = ((q5) ^ fx) * 8;             // k-step 0: pk = q5
  kp[1] = ((2 + q5) ^ fx) * 8;         // k-step 1: pk = 2 + q5
  int arb[4], brb[2];
#pragma unroll
  for (int t = 0; t < 4; ++t) arb[t] = (wm * 128 + t * 32 + rr) * 32;
#pragma unroll
  for (int c = 0; c < 2; ++c) brb[c] = (wn * 64 + c * 32 + rr) * 32;

  f32x16 acc[4][2] = {};
  bf16x8 aR0[4][2], bR0[2][2], aR1[4][2], bR1[2][2];

  STAGE(0, t0 + 0); STAGE(1, t0 + 1); STAGE(2, t0 + 2);
  VMC(4); BAR();
  READ_SET(aR0, bR0, 0);

  for (int it = 0; it < 48; ++it) {
    const int u = it * 2;
    READ_SET(aR1, bR1, (u + 1) & 3);
    STAGE((u + 3) & 3, t0 + u + 3);
    SP(1); MFMA_SET(aR0, bR0); SP(0);
    VMC(4); SB0(); BAR();
    READ_SET(aR0, bR0, (u + 2) & 3);
    STAGE((u + 4) & 3, t0 + u + 4);
    SP(1); MFMA_SET(aR1, bR1); SP(0);
    VMC(4); SB0(); BAR();
  }
  READ_SET(aR1, bR1, 1);
  STAGE(3, t0 + 99);
  SP(1); MFMA_SET(aR0, bR0); SP(0);
  VMC(4); SB0(); BAR();
  READ_SET(aR0, bR0, 2);
  SP(1); MFMA_SET(aR1, bR1); SP(0);
  VMC(0); SB0(); BAR();
  READ_SET(aR1, bR1, 3);
  SP(1); MFMA_SET(aR0, bR0); SP(0);
  MFMA_SET(aR1, bR1);

  // epilogue: C/D 32x32 mapping (m74/m101): col=lane&31,
  // row=(reg&3)+8*(reg>>2)+4*(lane>>5)
  unsigned short* P = Pp + kid * 8388608;
#pragma unroll
  for (int t = 0; t < 4; ++t) {
#pragma unroll
    for (int c = 0; c < 2; ++c) {
      int col = wn * 64 + c * 32 + rr;
#pragma unroll
      for (int r = 0; r < 16; ++r) {
        int row = m0 + wm * 128 + t * 32 + (r & 3) + ((r >> 2) << 3) + (q5 << 2);
        P[(size_t)row * 256 + col] = f2bf(acc[t][c][r]);
      }
    }
  }
}

// --- K3: tail, scalarized weights (r11 config) ------------------------------
__global__ __launch_bounds__(128) void tail_k4(
    const unsigned short* __restrict__ Pp, const float* __restrict__ y,
    const float* __restrict__ bp, const float* __restrict__ cbp,
    const float* __restrict__ Ws, const float* __restrict__ bs,
    const float* __restrict__ cbs,
    const float* __restrict__ Wr1, const float* __restrict__ br1,
    const float* __restrict__ Wr2, const float* __restrict__ br2,
    const float* __restrict__ Wr3, const float* __restrict__ br3,
    float* __restrict__ out) {
  __shared__ float pp[2][64][8];
  __shared__ float r1l[64][65];
  __shared__ float snk[2][64];

  const int tid = threadIdx.x;
  const int w = __builtin_amdgcn_readfirstlane(tid >> 6);
  const int l = tid & 63;
  const int m = blockIdx.x * 64 + l;

  const us8* pr0 = (const us8*)(Pp + (size_t)m * 256) + w * 16;
  const us8* pr1 = (const us8*)(Pp + 8388608 + (size_t)m * 256) + w * 16;
  float P8[8] = {0.f, 0.f, 0.f, 0.f, 0.f, 0.f, 0.f, 0.f};
#pragma unroll 4
  for (int i = 0; i < 16; ++i) {
    const int ci = (w * 16 + i) * 8;
    us8 a = pr0[i], b = pr1[i];
    float v[8];
#pragma unroll
    for (int c = 0; c < 8; ++c)
      v[c] = (bf2f(a[c]) + bf2f(b[c])) * (1.f / 32.f)
           + (bp[ci + c] * (1.f / 32.f) + cbp[ci + c]);
    float sqa = v[0]*v[0] + v[1]*v[1] + v[2]*v[2] + v[3]*v[3];
    float sqb = v[4]*v[4] + v[5]*v[5] + v[6]*v[6] + v[7]*v[7];
    float sq = sqa + sqb;
    float scale = sq / ((1.f + sq) * sqrtf(sq + 1e-9f));
#pragma unroll
    for (int c = 0; c < 8; ++c) P8[c] += v[c] * scale;
  }
#pragma unroll
  for (int c = 0; c < 8; ++c) pp[w][l][c] = P8[c];
  __syncthreads();
#pragma unroll
  for (int c = 0; c < 8; ++c) P8[c] = pp[0][l][c] + pp[1][l][c];

  float pre[16];
  float sqx = 0.f, sqy = 0.f;
#pragma unroll
  for (int a = 0; a < 16; ++a) {
    float s0 = P8[0]*Ws[a*8+0] + P8[1]*Ws[a*8+1] + P8[2]*Ws[a*8+2] + P8[3]*Ws[a*8+3];
    float s1 = P8[4]*Ws[a*8+4] + P8[5]*Ws[a*8+5] + P8[6]*Ws[a*8+6] + P8[7]*Ws[a*8+7];
    float s = (32.f * bs[a] + cbs[a]) + s0 + s1;
    pre[a] = s;
    if (a & 1) sqy += s * s; else sqx += s * s;
  }
  float sq2 = sqx + sqy;
  float sc2 = sq2 / ((1.f + sq2) * sqrtf(sq2 + 1e-9f));
  if (w == 0) out[m] = sqrtf(sq2 * sc2 * sc2 + 1e-9f);

  const float f = sc2 * y[m];
  float pf[16];
#pragma unroll
  for (int a = 0; a < 16; ++a) pf[a] = pre[a] * f;

#pragma unroll
  for (int jj = 0; jj < 32; ++jj) {
    const int j = w * 32 + jj;
    float s0 = 0.f, s1 = 0.f;
#pragma unroll
    for (int a = 0; a < 8; ++a) {
      s0 += pf[a] * Wr1[j * 16 + a];
      s1 += pf[a + 8] * Wr1[j * 16 + a + 8];
    }
    r1l[l][j] = fmaxf(br1[j] + s0 + s1, 0.f);
  }
  __syncthreads();
  float r1f[64];
#pragma unroll
  for (int j = 0; j < 64; ++j) r1f[j] = r1l[l][j];

  float a0 = 0.f, a1 = 0.f, a2 = 0.f, a3 = 0.f;
#pragma unroll 4
  for (int kk = 0; kk < 64; ++kk) {
    const int k = w * 64 + kk;
    const float* wr = Wr2 + k * 64;
    float s0 = 0.f, s1 = 0.f, s2 = 0.f, s3 = 0.f;
#pragma unroll
    for (int j = 0; j < 16; ++j) {
      s0 += r1f[j] * wr[j];           s1 += r1f[j + 16] * wr[j + 16];
      s2 += r1f[j + 32] * wr[j + 32]; s3 += r1f[j + 48] * wr[j + 48];
    }
    float s = br2[k] + (s0 + s1) + (s2 + s3);
    float t = fmaxf(s, 0.f) * Wr3[k];
    switch (kk & 3) { case 0: a0 += t; break; case 1: a1 += t; break;
                      case 2: a2 += t; break; default: a3 += t; }
  }
  float own = (a0 + a1) + (a2 + a3);
  snk[w][l] = own;
  __syncthreads();
  if (w == 0) {
    float acc2 = br3[0] + own + snk[1][l];
    out[32768 + m] = 1.f / (1.f + expf(-acc2));
  }
}

// ---------------------------------------------------------------------------
extern "C" void kernel_launch(void* const* d_in, const int* in_sizes, int n_in,
                              void* d_out, int out_size, void* d_ws, size_t ws_size,
                              hipStream_t stream) {
  const float* x   = (const float*)d_in[0];
  const float* y   = (const float*)d_in[1];
  const float* W1  = (const float*)d_in[2];
  const float* b1  = (const float*)d_in[3];
  const float* Wp  = (const float*)d_in[4];
  const float* bp  = (const float*)d_in[5];
  const float* cbp = (const float*)d_in[6];
  const float* Ws  = (const float*)d_in[7];
  const float* bs  = (const float*)d_in[8];
  const float* cbs = (const float*)d_in[9];
  const float* Wr1 = (const float*)d_in[10];
  const float* br1 = (const float*)d_in[11];
  const float* Wr2 = (const float*)d_in[12];
  const float* br2 = (const float*)d_in[13];
  const float* Wr3 = (const float*)d_in[14];
  const float* br3 = (const float*)d_in[15];
  float* out = (float*)d_out;

  char* ws = (char*)d_ws;
  unsigned short* Apad = (unsigned short*)ws;
  unsigned short* BT   = (unsigned short*)(ws + BT_OFF);
  unsigned short* Pp   = (unsigned short*)(ws + PP_OFF);

  hipLaunchKernelGGL(pre_k, dim3(4612), dim3(256), 0, stream, x, W1, b1, Wp, BT, Apad);
  hipLaunchKernelGGL(caps_conv2, dim3(256), dim3(512), 0, stream, Apad, BT, Pp);
  hipLaunchKernelGGL(tail_k4, dim3(512), dim3(128), 0, stream,
                     Pp, y, bp, cbp, Ws, bs, cbs, Wr1, br1, Wr2, br2, Wr3, br3, out);
}

// Round 14
// 155.349 us; speedup vs baseline: 1.5127x; 1.0145x over previous
//
#include <hip/hip_runtime.h>
#include <hip/hip_bf16.h>

typedef __attribute__((ext_vector_type(8))) unsigned short us8;
typedef __attribute__((ext_vector_type(8))) __bf16 bf16x8;
typedef __attribute__((ext_vector_type(4))) float f32x4;

__device__ __forceinline__ unsigned short f2bf(float f) {
  unsigned int u = __float_as_uint(f);
  u += 0x7FFFu + ((u >> 16) & 1u);   // round-to-nearest-even
  return (unsigned short)(u >> 16);
}
__device__ __forceinline__ float bf2f(unsigned short u) {
  return __uint_as_float(((unsigned int)u) << 16);
}

// direct global->LDS DMA, 16B per lane (dest = wave-uniform base + lane*16)
__device__ __forceinline__ void gld16(const unsigned short* g, unsigned short* l) {
  __builtin_amdgcn_global_load_lds(reinterpret_cast<const unsigned int*>(g),
                                   reinterpret_cast<unsigned int*>(l), 16, 0, 0);
}

// ---------------------------------------------------------------------------
// ws layout (bytes)
//   Apad : [2][132][132][256] bf16 = 17,842,176
//   BT   : [256][6400] bf16 (k=(dh*5+dw)*256+c)
//   Pp   : 2 x [32768][256] bf16 partials = 33,554,432
// total = 54,673,408
// ---------------------------------------------------------------------------
#define BT_OFF     17842176
#define PP_OFF     21118976

// --- K1: fused conv1 (blocks 0..511) + weight prep (512..767) +
//         halo zero (768..1027) ---------------------------------------------
// conv1: 64 pixels/block, patch loaded ONCE per thread, W1 wave-uniform
// (scalar loads), output staged in LDS (XOR part-swizzle, 2-way max) then
// flushed with 32 lanes per full 512B pixel row -> perfectly coalesced.
__global__ __launch_bounds__(256) void pre_k(const float* __restrict__ x,
                                             const float* __restrict__ W1,
                                             const float* __restrict__ b1,
                                             const float* __restrict__ Wp,
                                             unsigned short* __restrict__ BT,
                                             unsigned short* __restrict__ Apad) {
  __shared__ __attribute__((aligned(16))) char shm[32768];
  const int bid = blockIdx.x, t = threadIdx.x;
  if (bid < 512) {
    unsigned short* obuf = (unsigned short*)shm;   // [64 rows][256] us
    const int l = t & 63;                          // lane = local pixel
    const int w4 = __builtin_amdgcn_readfirstlane(t >> 6);  // wave 0..3
    const int px0 = bid << 6;
    {
      const int p = px0 + l;
      const int b = p >> 14, hw = p & 16383;
      const int h = hw >> 7, wc = hw & 127;
      float patch[25];
#pragma unroll
      for (int dh = 0; dh < 5; ++dh)
#pragma unroll
        for (int dw = 0; dw < 5; ++dw) {
          int hh = h + dh - 2, ww = wc + dw - 2;
          bool ok = (hh >= 0) & (hh < 128) & (ww >= 0) & (ww < 128);
          patch[dh * 5 + dw] = ok ? x[(b << 14) + hh * 128 + ww] : 0.f;
        }
      // 8 channel-group iterations; co0 wave-uniform -> W1/b1 scalarize
#pragma unroll
      for (int cg = 0; cg < 8; ++cg) {
        const int co0 = cg * 32 + w4 * 8;
        us8 o;
#pragma unroll
        for (int c = 0; c < 8; ++c) {
          float acc = b1[co0 + c];
#pragma unroll
          for (int i = 0; i < 25; ++i) acc += patch[i] * W1[(co0 + c) * 25 + i];
          o[c] = f2bf(fmaxf(acc, 0.f));
        }
        const int pt = co0 >> 3;                     // 16B part id (uniform)
        *(us8*)&obuf[l * 256 + ((pt ^ (l & 31)) << 3)] = o;
      }
    }
    __syncthreads();
    // coalesced flush: iter i, 32 lanes write one full 512B pixel row
#pragma unroll
    for (int i = 0; i < 8; ++i) {
      const int row = (t >> 5) + i * 8;              // 0..63
      const int ptg = t & 31;                        // global part
      us8 v = *(const us8*)&obuf[row * 256 + ((ptg ^ (row & 31)) << 3)];
      const int p = px0 + row;
      const int b = p >> 14, hw = p & 16383;
      const int h = hw >> 7, wc = hw & 127;
      *(us8*)(Apad + (size_t)((b * 132 + h + 2) * 132 + (wc + 2)) * 256 + ptg * 8) = v;
    }
  } else if (bid < 768) {
    float* w = (float*)shm;
    const int n = bid - 512;
    const float* src = Wp + n * 6400;
    for (int i = t; i < 6400; i += 256) w[i] = src[i];
    __syncthreads();
    for (int k = t; k < 6400; k += 256) {
      int dhw = k >> 8, c = k & 255;
      BT[n * 6400 + k] = f2bf(w[c * 25 + dhw]);
    }
  } else {
    int idx = (bid - 768) * 256 + t;
    int chunk = idx & 31;
    int pix = idx >> 5;
    int img = pix >= 1040;
    int p = pix - img * 1040;
    int h, w2;
    if (p < 528) {
      int rs = p / 132;
      h = (rs < 2) ? rs : rs + 128;
      w2 = p - rs * 132;
    } else {
      int q = p - 528;
      h = 2 + (q >> 2);
      int cs = q & 3;
      w2 = (cs < 2) ? cs : cs + 128;
    }
    us8 z = {0, 0, 0, 0, 0, 0, 0, 0};
    *(us8*)(Apad + (size_t)(img * 17424 + h * 132 + w2) * 256 + chunk * 8) = z;
  }
}

// --- K2: implicit-GEMM conv (EXACT r8/r11 config: 96.8us, MfmaUtil 47) -----
// 256x256 tile, 8 waves, split-K=2, 4-slot BK=32 ring (A+B in LDS, 128 KB),
// reg-double-buffered frags, ONE barrier + ONE counted VMC(4) per k-unit.
#define STAGE(slot, ku) do { int dhw_=(ku)>>3, dh_=dhw_/5, dw_=dhw_-dh_*5;     \
    int ao_=((dh_*132+dw_)<<8)+(((ku)&7)<<5);                                  \
    int kp_=(ku)<<5;                                                           \
    gld16(Aap+abase0+ao_, &As[slot][sA]);                                      \
    gld16(Aap+abase1+ao_, &As[slot][sA+4096]);                                 \
    gld16(BT+bbase0+kp_, &Bs[slot][sA]);                                       \
    gld16(BT+bbase1+kp_, &Bs[slot][sA+4096]); } while(0)
#define READ_SET(AST, BST, slot) do {                                          \
  _Pragma("unroll") for (int s_ = 0; s_ < 8; ++s_)                             \
    AST[s_] = *(const bf16x8*)(&As[slot][areadbase + s_*512]);                 \
  _Pragma("unroll") for (int j_ = 0; j_ < 4; ++j_)                             \
    BST[j_] = *(const bf16x8*)(&Bs[slot][breadbase + j_*512]); } while(0)
#define MFMA_SET(AST, BST) do {                                                \
  _Pragma("unroll") for (int s_ = 0; s_ < 8; ++s_)                             \
  _Pragma("unroll") for (int j_ = 0; j_ < 4; ++j_)                             \
    acc[s_][j_] = __builtin_amdgcn_mfma_f32_16x16x32_bf16(                     \
        AST[s_], BST[j_], acc[s_][j_], 0, 0, 0); } while(0)
#define BAR() __builtin_amdgcn_s_barrier()
#define VMC(n) asm volatile("s_waitcnt vmcnt(" #n ")" ::: "memory")
#define SB0() __builtin_amdgcn_sched_barrier(0)
#define SP(n) __builtin_amdgcn_s_setprio(n)

__global__ __launch_bounds__(512, 1) void caps_conv2(
    const unsigned short* __restrict__ Aap,  // Apad NHWC bf16
    const unsigned short* __restrict__ BT,   // [256][6400] bf16
    unsigned short* __restrict__ Pp)         // 2 x [32768][256] bf16 partials
{
  __shared__ __attribute__((aligned(16))) unsigned short As[4][8192];
  __shared__ __attribute__((aligned(16))) unsigned short Bs[4][8192];

  const int tid = threadIdx.x;
  const int bid = blockIdx.x;          // 256 blocks
  const int lid = (bid & 7) * 32 + (bid >> 3);   // bijective XCD-chunked swizzle
  const int kid = lid & 1;
  const int m0 = (lid >> 1) << 8;
  const int t0 = kid * 100;            // 100 k-units of 32 per split-K half
  const int wid = tid >> 6;
  const int l = tid & 63;

  const int swz = (l & 3) ^ ((l >> 3) & 3);   // matches read part q^((row>>1)&3)
  int abase0, abase1, bbase0, bbase1;
  {
    int ra = wid * 16 + (l >> 2);               // 0..127
    int m = m0 + ra;
    int b = m >> 14, hw = m & 16383, h = hw >> 7, w = hw & 127;
    abase0 = ((b * 132 + h) * 132 + w) * 256 + swz * 8;
    m = m0 + ra + 128;
    b = m >> 14; hw = m & 16383; h = hw >> 7; w = hw & 127;
    abase1 = ((b * 132 + h) * 132 + w) * 256 + swz * 8;
    bbase0 = ra * 6400 + swz * 8;
    bbase1 = (ra + 128) * 6400 + swz * 8;
  }
  const int sA = wid * 512;            // LDS stage base (ushorts)

  const int rl = l & 15, q = l >> 4;
  const int wm = wid >> 2, wn = wid & 3;       // 2x4 wave grid, tile 128x64
  const int areadbase = (wm * 128 + rl) * 32 + ((q ^ ((rl >> 1) & 3)) << 3);
  const int breadbase = (wn * 64 + rl) * 32 + ((q ^ ((rl >> 1) & 3)) << 3);

  f32x4 acc[8][4] = {};
  bf16x8 aR0[8], bR0[4], aR1[8], bR1[4];

  STAGE(0, t0 + 0); STAGE(1, t0 + 1); STAGE(2, t0 + 2);
  VMC(4); BAR();
  READ_SET(aR0, bR0, 0);

  for (int it = 0; it < 48; ++it) {
    const int u = it * 2;
    READ_SET(aR1, bR1, (u + 1) & 3);
    STAGE((u + 3) & 3, t0 + u + 3);
    SP(1); MFMA_SET(aR0, bR0); SP(0);
    VMC(4); SB0(); BAR();
    READ_SET(aR0, bR0, (u + 2) & 3);
    STAGE((u + 4) & 3, t0 + u + 4);
    SP(1); MFMA_SET(aR1, bR1); SP(0);
    VMC(4); SB0(); BAR();
  }
  READ_SET(aR1, bR1, 1);
  STAGE(3, t0 + 99);
  SP(1); MFMA_SET(aR0, bR0); SP(0);
  VMC(4); SB0(); BAR();
  READ_SET(aR0, bR0, 2);
  SP(1); MFMA_SET(aR1, bR1); SP(0);
  VMC(0); SB0(); BAR();
  READ_SET(aR1, bR1, 3);
  SP(1); MFMA_SET(aR0, bR0); SP(0);
  MFMA_SET(aR1, bR1);

  unsigned short* P = Pp + kid * 8388608;
#pragma unroll
  for (int s = 0; s < 8; ++s) {
#pragma unroll
    for (int j = 0; j < 4; ++j) {
      int col = wn * 64 + j * 16 + rl;
      int mrow = m0 + wm * 128 + s * 16 + (q << 2);
#pragma unroll
      for (int e = 0; e < 4; ++e)
        P[(size_t)(mrow + e) * 256 + col] = f2bf(acc[s][j][e]);
    }
  }
}

// --- K3: tail, scalarized weights (r11 config) ------------------------------
__global__ __launch_bounds__(128) void tail_k4(
    const unsigned short* __restrict__ Pp, const float* __restrict__ y,
    const float* __restrict__ bp, const float* __restrict__ cbp,
    const float* __restrict__ Ws, const float* __restrict__ bs,
    const float* __restrict__ cbs,
    const float* __restrict__ Wr1, const float* __restrict__ br1,
    const float* __restrict__ Wr2, const float* __restrict__ br2,
    const float* __restrict__ Wr3, const float* __restrict__ br3,
    float* __restrict__ out) {
  __shared__ float pp[2][64][8];
  __shared__ float r1l[64][65];
  __shared__ float snk[2][64];

  const int tid = threadIdx.x;
  const int w = __builtin_amdgcn_readfirstlane(tid >> 6);
  const int l = tid & 63;
  const int m = blockIdx.x * 64 + l;

  const us8* pr0 = (const us8*)(Pp + (size_t)m * 256) + w * 16;
  const us8* pr1 = (const us8*)(Pp + 8388608 + (size_t)m * 256) + w * 16;
  float P8[8] = {0.f, 0.f, 0.f, 0.f, 0.f, 0.f, 0.f, 0.f};
#pragma unroll 4
  for (int i = 0; i < 16; ++i) {
    const int ci = (w * 16 + i) * 8;
    us8 a = pr0[i], b = pr1[i];
    float v[8];
#pragma unroll
    for (int c = 0; c < 8; ++c)
      v[c] = (bf2f(a[c]) + bf2f(b[c])) * (1.f / 32.f)
           + (bp[ci + c] * (1.f / 32.f) + cbp[ci + c]);
    float sqa = v[0]*v[0] + v[1]*v[1] + v[2]*v[2] + v[3]*v[3];
    float sqb = v[4]*v[4] + v[5]*v[5] + v[6]*v[6] + v[7]*v[7];
    float sq = sqa + sqb;
    float scale = sq / ((1.f + sq) * sqrtf(sq + 1e-9f));
#pragma unroll
    for (int c = 0; c < 8; ++c) P8[c] += v[c] * scale;
  }
#pragma unroll
  for (int c = 0; c < 8; ++c) pp[w][l][c] = P8[c];
  __syncthreads();
#pragma unroll
  for (int c = 0; c < 8; ++c) P8[c] = pp[0][l][c] + pp[1][l][c];

  float pre[16];
  float sqx = 0.f, sqy = 0.f;
#pragma unroll
  for (int a = 0; a < 16; ++a) {
    float s0 = P8[0]*Ws[a*8+0] + P8[1]*Ws[a*8+1] + P8[2]*Ws[a*8+2] + P8[3]*Ws[a*8+3];
    float s1 = P8[4]*Ws[a*8+4] + P8[5]*Ws[a*8+5] + P8[6]*Ws[a*8+6] + P8[7]*Ws[a*8+7];
    float s = (32.f * bs[a] + cbs[a]) + s0 + s1;
    pre[a] = s;
    if (a & 1) sqy += s * s; else sqx += s * s;
  }
  float sq2 = sqx + sqy;
  float sc2 = sq2 / ((1.f + sq2) * sqrtf(sq2 + 1e-9f));
  if (w == 0) out[m] = sqrtf(sq2 * sc2 * sc2 + 1e-9f);

  const float f = sc2 * y[m];
  float pf[16];
#pragma unroll
  for (int a = 0; a < 16; ++a) pf[a] = pre[a] * f;

#pragma unroll
  for (int jj = 0; jj < 32; ++jj) {
    const int j = w * 32 + jj;
    float s0 = 0.f, s1 = 0.f;
#pragma unroll
    for (int a = 0; a < 8; ++a) {
      s0 += pf[a] * Wr1[j * 16 + a];
      s1 += pf[a + 8] * Wr1[j * 16 + a + 8];
    }
    r1l[l][j] = fmaxf(br1[j] + s0 + s1, 0.f);
  }
  __syncthreads();
  float r1f[64];
#pragma unroll
  for (int j = 0; j < 64; ++j) r1f[j] = r1l[l][j];

  float a0 = 0.f, a1 = 0.f, a2 = 0.f, a3 = 0.f;
#pragma unroll 4
  for (int kk = 0; kk < 64; ++kk) {
    const int k = w * 64 + kk;
    const float* wr = Wr2 + k * 64;
    float s0 = 0.f, s1 = 0.f, s2 = 0.f, s3 = 0.f;
#pragma unroll
    for (int j = 0; j < 16; ++j) {
      s0 += r1f[j] * wr[j];           s1 += r1f[j + 16] * wr[j + 16];
      s2 += r1f[j + 32] * wr[j + 32]; s3 += r1f[j + 48] * wr[j + 48];
    }
    float s = br2[k] + (s0 + s1) + (s2 + s3);
    float t = fmaxf(s, 0.f) * Wr3[k];
    switch (kk & 3) { case 0: a0 += t; break; case 1: a1 += t; break;
                      case 2: a2 += t; break; default: a3 += t; }
  }
  float own = (a0 + a1) + (a2 + a3);
  snk[w][l] = own;
  __syncthreads();
  if (w == 0) {
    float acc2 = br3[0] + own + snk[1][l];
    out[32768 + m] = 1.f / (1.f + expf(-acc2));
  }
}

// ---------------------------------------------------------------------------
extern "C" void kernel_launch(void* const* d_in, const int* in_sizes, int n_in,
                              void* d_out, int out_size, void* d_ws, size_t ws_size,
                              hipStream_t stream) {
  const float* x   = (const float*)d_in[0];
  const float* y   = (const float*)d_in[1];
  const float* W1  = (const float*)d_in[2];
  const float* b1  = (const float*)d_in[3];
  const float* Wp  = (const float*)d_in[4];
  const float* bp  = (const float*)d_in[5];
  const float* cbp = (const float*)d_in[6];
  const float* Ws  = (const float*)d_in[7];
  const float* bs  = (const float*)d_in[8];
  const float* cbs = (const float*)d_in[9];
  const float* Wr1 = (const float*)d_in[10];
  const float* br1 = (const float*)d_in[11];
  const float* Wr2 = (const float*)d_in[12];
  const float* br2 = (const float*)d_in[13];
  const float* Wr3 = (const float*)d_in[14];
  const float* br3 = (const float*)d_in[15];
  float* out = (float*)d_out;

  char* ws = (char*)d_ws;
  unsigned short* Apad = (unsigned short*)ws;
  unsigned short* BT   = (unsigned short*)(ws + BT_OFF);
  unsigned short* Pp   = (unsigned short*)(ws + PP_OFF);

  hipLaunchKernelGGL(pre_k, dim3(1028), dim3(256), 0, stream, x, W1, b1, Wp, BT, Apad);
  hipLaunchKernelGGL(caps_conv2, dim3(256), dim3(512), 0, stream, Apad, BT, Pp);
  hipLaunchKernelGGL(tail_k4, dim3(512), dim3(128), 0, stream,
                     Pp, y, bp, cbp, Ws, bs, cbs, Wr1, br1, Wr2, br2, Wr3, br3, out);
}

// Round 15
// 144.815 us; speedup vs baseline: 1.6227x; 1.0727x over previous
//
#include <hip/hip_runtime.h>
#include <hip/hip_bf16.h>

typedef __attribute__((ext_vector_type(8))) unsigned short us8;
typedef __attribute__((ext_vector_type(8))) __bf16 bf16x8;
typedef __attribute__((ext_vector_type(4))) float f32x4;

__device__ __forceinline__ unsigned short f2bf(float f) {
  unsigned int u = __float_as_uint(f);
  u += 0x7FFFu + ((u >> 16) & 1u);   // round-to-nearest-even
  return (unsigned short)(u >> 16);
}
__device__ __forceinline__ float bf2f(unsigned short u) {
  return __uint_as_float(((unsigned int)u) << 16);
}

// direct global->LDS DMA, 16B per lane (dest = wave-uniform base + lane*16)
__device__ __forceinline__ void gld16(const unsigned short* g, unsigned short* l) {
  __builtin_amdgcn_global_load_lds(reinterpret_cast<const unsigned int*>(g),
                                   reinterpret_cast<unsigned int*>(l), 16, 0, 0);
}

// ---------------------------------------------------------------------------
// ws layout (bytes)
//   Apad : [2][132][132][256] bf16 = 17,842,176
//   BT   : [256][6400] bf16 (k=(dh*5+dw)*256+c)
//   Pp   : 2 x [32768][256] bf16 partials = 33,554,432
// total = 54,673,408
// ---------------------------------------------------------------------------
#define BT_OFF     17842176
#define PP_OFF     21118976

// --- K1: fused conv1 (blocks 0..4095) + weight prep (4096..4351) +
//         halo zero (4352..4611) --------------------------------------------
// (r11-exact: the 1M-thread high-TLP form; the 512-block LDS-staged rewrite
//  regressed ~11us — latency-bound behind serial scalar-load waits.)
__global__ __launch_bounds__(256) void pre_k(const float* __restrict__ x,
                                             const float* __restrict__ W1,
                                             const float* __restrict__ b1,
                                             const float* __restrict__ Wp,
                                             unsigned short* __restrict__ BT,
                                             unsigned short* __restrict__ Apad) {
  __shared__ float w[6400];
  const int bid = blockIdx.x, t = threadIdx.x;
  if (bid < 4096) {
    int pxt = bid >> 3;
    int cq  = bid & 7;
    int px  = (pxt << 6) + (t & 63);
    int cg  = __builtin_amdgcn_readfirstlane(t >> 6);
    int co0 = (cq << 5) + (cg << 3);
    int b = px >> 14, hw = px & 16383;
    int h = hw >> 7, wcol = hw & 127;

    float patch[25];
#pragma unroll
    for (int dh = 0; dh < 5; ++dh)
#pragma unroll
      for (int dw = 0; dw < 5; ++dw) {
        int hh = h + dh - 2, ww = wcol + dw - 2;
        bool ok = (hh >= 0) & (hh < 128) & (ww >= 0) & (ww < 128);
        patch[dh * 5 + dw] = ok ? x[(b << 14) + hh * 128 + ww] : 0.f;
      }
    us8 o;
#pragma unroll
    for (int c = 0; c < 8; ++c) {
      float acc = b1[co0 + c];
#pragma unroll
      for (int i = 0; i < 25; ++i) acc += patch[i] * W1[(co0 + c) * 25 + i];
      o[c] = f2bf(fmaxf(acc, 0.f));
    }
    *(us8*)(Apad + (size_t)((b * 132 + h + 2) * 132 + (wcol + 2)) * 256 + co0) = o;
  } else if (bid < 4352) {
    const int n = bid - 4096;
    const float* src = Wp + n * 6400;
    for (int i = t; i < 6400; i += 256) w[i] = src[i];
    __syncthreads();
    for (int k = t; k < 6400; k += 256) {
      int dhw = k >> 8, c = k & 255;
      BT[n * 6400 + k] = f2bf(w[c * 25 + dhw]);
    }
  } else {
    int idx = (bid - 4352) * 256 + t;
    int chunk = idx & 31;
    int pix = idx >> 5;
    int img = pix >= 1040;
    int p = pix - img * 1040;
    int h, w2;
    if (p < 528) {
      int rs = p / 132;
      h = (rs < 2) ? rs : rs + 128;
      w2 = p - rs * 132;
    } else {
      int q = p - 528;
      h = 2 + (q >> 2);
      int cs = q & 3;
      w2 = (cs < 2) ? cs : cs + 128;
    }
    us8 z = {0, 0, 0, 0, 0, 0, 0, 0};
    *(us8*)(Apad + (size_t)(img * 17424 + h * 132 + w2) * 256 + chunk * 8) = z;
  }
}

// --- K2: implicit-GEMM conv (EXACT r8/r11 config: 96.8us, MfmaUtil 47) -----
// 256x256 tile, 8 waves, split-K=2, 4-slot BK=32 ring (A+B in LDS, 128 KB),
// reg-double-buffered frags, ONE barrier + ONE counted VMC(4) per k-unit.
#define STAGE(slot, ku) do { int dhw_=(ku)>>3, dh_=dhw_/5, dw_=dhw_-dh_*5;     \
    int ao_=((dh_*132+dw_)<<8)+(((ku)&7)<<5);                                  \
    int kp_=(ku)<<5;                                                           \
    gld16(Aap+abase0+ao_, &As[slot][sA]);                                      \
    gld16(Aap+abase1+ao_, &As[slot][sA+4096]);                                 \
    gld16(BT+bbase0+kp_, &Bs[slot][sA]);                                       \
    gld16(BT+bbase1+kp_, &Bs[slot][sA+4096]); } while(0)
#define READ_SET(AST, BST, slot) do {                                          \
  _Pragma("unroll") for (int s_ = 0; s_ < 8; ++s_)                             \
    AST[s_] = *(const bf16x8*)(&As[slot][areadbase + s_*512]);                 \
  _Pragma("unroll") for (int j_ = 0; j_ < 4; ++j_)                             \
    BST[j_] = *(const bf16x8*)(&Bs[slot][breadbase + j_*512]); } while(0)
#define MFMA_SET(AST, BST) do {                                                \
  _Pragma("unroll") for (int s_ = 0; s_ < 8; ++s_)                             \
  _Pragma("unroll") for (int j_ = 0; j_ < 4; ++j_)                             \
    acc[s_][j_] = __builtin_amdgcn_mfma_f32_16x16x32_bf16(                     \
        AST[s_], BST[j_], acc[s_][j_], 0, 0, 0); } while(0)
#define BAR() __builtin_amdgcn_s_barrier()
#define VMC(n) asm volatile("s_waitcnt vmcnt(" #n ")" ::: "memory")
#define SB0() __builtin_amdgcn_sched_barrier(0)
#define SP(n) __builtin_amdgcn_s_setprio(n)

__global__ __launch_bounds__(512, 1) void caps_conv2(
    const unsigned short* __restrict__ Aap,  // Apad NHWC bf16
    const unsigned short* __restrict__ BT,   // [256][6400] bf16
    unsigned short* __restrict__ Pp)         // 2 x [32768][256] bf16 partials
{
  __shared__ __attribute__((aligned(16))) unsigned short As[4][8192];
  __shared__ __attribute__((aligned(16))) unsigned short Bs[4][8192];

  const int tid = threadIdx.x;
  const int bid = blockIdx.x;          // 256 blocks
  const int lid = (bid & 7) * 32 + (bid >> 3);   // bijective XCD-chunked swizzle
  const int kid = lid & 1;
  const int m0 = (lid >> 1) << 8;
  const int t0 = kid * 100;            // 100 k-units of 32 per split-K half
  const int wid = tid >> 6;
  const int l = tid & 63;

  const int swz = (l & 3) ^ ((l >> 3) & 3);   // matches read part q^((row>>1)&3)
  int abase0, abase1, bbase0, bbase1;
  {
    int ra = wid * 16 + (l >> 2);               // 0..127
    int m = m0 + ra;
    int b = m >> 14, hw = m & 16383, h = hw >> 7, w = hw & 127;
    abase0 = ((b * 132 + h) * 132 + w) * 256 + swz * 8;
    m = m0 + ra + 128;
    b = m >> 14; hw = m & 16383; h = hw >> 7; w = hw & 127;
    abase1 = ((b * 132 + h) * 132 + w) * 256 + swz * 8;
    bbase0 = ra * 6400 + swz * 8;
    bbase1 = (ra + 128) * 6400 + swz * 8;
  }
  const int sA = wid * 512;            // LDS stage base (ushorts)

  const int rl = l & 15, q = l >> 4;
  const int wm = wid >> 2, wn = wid & 3;       // 2x4 wave grid, tile 128x64
  const int areadbase = (wm * 128 + rl) * 32 + ((q ^ ((rl >> 1) & 3)) << 3);
  const int breadbase = (wn * 64 + rl) * 32 + ((q ^ ((rl >> 1) & 3)) << 3);

  f32x4 acc[8][4] = {};
  bf16x8 aR0[8], bR0[4], aR1[8], bR1[4];

  STAGE(0, t0 + 0); STAGE(1, t0 + 1); STAGE(2, t0 + 2);
  VMC(4); BAR();
  READ_SET(aR0, bR0, 0);

  for (int it = 0; it < 48; ++it) {
    const int u = it * 2;
    READ_SET(aR1, bR1, (u + 1) & 3);
    STAGE((u + 3) & 3, t0 + u + 3);
    SP(1); MFMA_SET(aR0, bR0); SP(0);
    VMC(4); SB0(); BAR();
    READ_SET(aR0, bR0, (u + 2) & 3);
    STAGE((u + 4) & 3, t0 + u + 4);
    SP(1); MFMA_SET(aR1, bR1); SP(0);
    VMC(4); SB0(); BAR();
  }
  READ_SET(aR1, bR1, 1);
  STAGE(3, t0 + 99);
  SP(1); MFMA_SET(aR0, bR0); SP(0);
  VMC(4); SB0(); BAR();
  READ_SET(aR0, bR0, 2);
  SP(1); MFMA_SET(aR1, bR1); SP(0);
  VMC(0); SB0(); BAR();
  READ_SET(aR1, bR1, 3);
  SP(1); MFMA_SET(aR0, bR0); SP(0);
  MFMA_SET(aR1, bR1);

  unsigned short* P = Pp + kid * 8388608;
#pragma unroll
  for (int s = 0; s < 8; ++s) {
#pragma unroll
    for (int j = 0; j < 4; ++j) {
      int col = wn * 64 + j * 16 + rl;
      int mrow = m0 + wm * 128 + s * 16 + (q << 2);
#pragma unroll
      for (int e = 0; e < 4; ++e)
        P[(size_t)(mrow + e) * 256 + col] = f2bf(acc[s][j][e]);
    }
  }
}

// --- K3: tail, scalarized weights (r11 config) ------------------------------
__global__ __launch_bounds__(128) void tail_k4(
    const unsigned short* __restrict__ Pp, const float* __restrict__ y,
    const float* __restrict__ bp, const float* __restrict__ cbp,
    const float* __restrict__ Ws, const float* __restrict__ bs,
    const float* __restrict__ cbs,
    const float* __restrict__ Wr1, const float* __restrict__ br1,
    const float* __restrict__ Wr2, const float* __restrict__ br2,
    const float* __restrict__ Wr3, const float* __restrict__ br3,
    float* __restrict__ out) {
  __shared__ float pp[2][64][8];
  __shared__ float r1l[64][65];
  __shared__ float snk[2][64];

  const int tid = threadIdx.x;
  const int w = __builtin_amdgcn_readfirstlane(tid >> 6);
  const int l = tid & 63;
  const int m = blockIdx.x * 64 + l;

  const us8* pr0 = (const us8*)(Pp + (size_t)m * 256) + w * 16;
  const us8* pr1 = (const us8*)(Pp + 8388608 + (size_t)m * 256) + w * 16;
  float P8[8] = {0.f, 0.f, 0.f, 0.f, 0.f, 0.f, 0.f, 0.f};
#pragma unroll 4
  for (int i = 0; i < 16; ++i) {
    const int ci = (w * 16 + i) * 8;
    us8 a = pr0[i], b = pr1[i];
    float v[8];
#pragma unroll
    for (int c = 0; c < 8; ++c)
      v[c] = (bf2f(a[c]) + bf2f(b[c])) * (1.f / 32.f)
           + (bp[ci + c] * (1.f / 32.f) + cbp[ci + c]);
    float sqa = v[0]*v[0] + v[1]*v[1] + v[2]*v[2] + v[3]*v[3];
    float sqb = v[4]*v[4] + v[5]*v[5] + v[6]*v[6] + v[7]*v[7];
    float sq = sqa + sqb;
    float scale = sq / ((1.f + sq) * sqrtf(sq + 1e-9f));
#pragma unroll
    for (int c = 0; c < 8; ++c) P8[c] += v[c] * scale;
  }
#pragma unroll
  for (int c = 0; c < 8; ++c) pp[w][l][c] = P8[c];
  __syncthreads();
#pragma unroll
  for (int c = 0; c < 8; ++c) P8[c] = pp[0][l][c] + pp[1][l][c];

  float pre[16];
  float sqx = 0.f, sqy = 0.f;
#pragma unroll
  for (int a = 0; a < 16; ++a) {
    float s0 = P8[0]*Ws[a*8+0] + P8[1]*Ws[a*8+1] + P8[2]*Ws[a*8+2] + P8[3]*Ws[a*8+3];
    float s1 = P8[4]*Ws[a*8+4] + P8[5]*Ws[a*8+5] + P8[6]*Ws[a*8+6] + P8[7]*Ws[a*8+7];
    float s = (32.f * bs[a] + cbs[a]) + s0 + s1;
    pre[a] = s;
    if (a & 1) sqy += s * s; else sqx += s * s;
  }
  float sq2 = sqx + sqy;
  float sc2 = sq2 / ((1.f + sq2) * sqrtf(sq2 + 1e-9f));
  if (w == 0) out[m] = sqrtf(sq2 * sc2 * sc2 + 1e-9f);

  const float f = sc2 * y[m];
  float pf[16];
#pragma unroll
  for (int a = 0; a < 16; ++a) pf[a] = pre[a] * f;

#pragma unroll
  for (int jj = 0; jj < 32; ++jj) {
    const int j = w * 32 + jj;
    float s0 = 0.f, s1 = 0.f;
#pragma unroll
    for (int a = 0; a < 8; ++a) {
      s0 += pf[a] * Wr1[j * 16 + a];
      s1 += pf[a + 8] * Wr1[j * 16 + a + 8];
    }
    r1l[l][j] = fmaxf(br1[j] + s0 + s1, 0.f);
  }
  __syncthreads();
  float r1f[64];
#pragma unroll
  for (int j = 0; j < 64; ++j) r1f[j] = r1l[l][j];

  float a0 = 0.f, a1 = 0.f, a2 = 0.f, a3 = 0.f;
#pragma unroll 4
  for (int kk = 0; kk < 64; ++kk) {
    const int k = w * 64 + kk;
    const float* wr = Wr2 + k * 64;
    float s0 = 0.f, s1 = 0.f, s2 = 0.f, s3 = 0.f;
#pragma unroll
    for (int j = 0; j < 16; ++j) {
      s0 += r1f[j] * wr[j];           s1 += r1f[j + 16] * wr[j + 16];
      s2 += r1f[j + 32] * wr[j + 32]; s3 += r1f[j + 48] * wr[j + 48];
    }
    float s = br2[k] + (s0 + s1) + (s2 + s3);
    float t = fmaxf(s, 0.f) * Wr3[k];
    switch (kk & 3) { case 0: a0 += t; break; case 1: a1 += t; break;
                      case 2: a2 += t; break; default: a3 += t; }
  }
  float own = (a0 + a1) + (a2 + a3);
  snk[w][l] = own;
  __syncthreads();
  if (w == 0) {
    float acc2 = br3[0] + own + snk[1][l];
    out[32768 + m] = 1.f / (1.f + expf(-acc2));
  }
}

// ---------------------------------------------------------------------------
extern "C" void kernel_launch(void* const* d_in, const int* in_sizes, int n_in,
                              void* d_out, int out_size, void* d_ws, size_t ws_size,
                              hipStream_t stream) {
  const float* x   = (const float*)d_in[0];
  const float* y   = (const float*)d_in[1];
  const float* W1  = (const float*)d_in[2];
  const float* b1  = (const float*)d_in[3];
  const float* Wp  = (const float*)d_in[4];
  const float* bp  = (const float*)d_in[5];
  const float* cbp = (const float*)d_in[6];
  const float* Ws  = (const float*)d_in[7];
  const float* bs  = (const float*)d_in[8];
  const float* cbs = (const float*)d_in[9];
  const float* Wr1 = (const float*)d_in[10];
  const float* br1 = (const float*)d_in[11];
  const float* Wr2 = (const float*)d_in[12];
  const float* br2 = (const float*)d_in[13];
  const float* Wr3 = (const float*)d_in[14];
  const float* br3 = (const float*)d_in[15];
  float* out = (float*)d_out;

  char* ws = (char*)d_ws;
  unsigned short* Apad = (unsigned short*)ws;
  unsigned short* BT   = (unsigned short*)(ws + BT_OFF);
  unsigned short* Pp   = (unsigned short*)(ws + PP_OFF);

  hipLaunchKernelGGL(pre_k, dim3(4612), dim3(256), 0, stream, x, W1, b1, Wp, BT, Apad);
  hipLaunchKernelGGL(caps_conv2, dim3(256), dim3(512), 0, stream, Apad, BT, Pp);
  hipLaunchKernelGGL(tail_k4, dim3(512), dim3(128), 0, stream,
                     Pp, y, bp, cbp, Ws, bs, cbs, Wr1, br1, Wr2, br2, Wr3, br3, out);
}